// Round 11
// baseline (288.880 us; speedup 1.0000x reference)
//
#include <hip/hip_runtime.h>
#include <math.h>

#define BDIM 256

constexpr int B_  = 4;
constexpr int L_  = 500;
constexpr int DM  = 1024;   // d_model
constexpr int DI  = 2048;   // d_inner
constexpr int DXZ = 4096;   // 2*d_inner
constexpr int RNK = 64;     // dt_rank
constexpr int NST = 16;     // d_state
constexpr int NXP = 96;     // dt_rank + 2*d_state
constexpr int M1  = B_ * L_;   // 2000 mamba tokens
constexpr int M2  = 200;       // fc1 rows (4*50)
constexpr int K2  = 10240;     // fc1 K
constexpr int NC  = 20;        // scan chunks
constexpr int LC  = L_ / NC;   // 25 steps per chunk

typedef __attribute__((ext_vector_type(8))) __bf16 bf16x8;
typedef __attribute__((ext_vector_type(4))) __bf16 bf16x4;
typedef __attribute__((ext_vector_type(4))) float  f32x4;

__device__ __forceinline__ float sigmoidf_(float x) { return 1.0f / (1.0f + __expf(-x)); }

// ---- one-time weight split: fp32 -> bf16 hi/lo ----
__global__ __launch_bounds__(BDIM)
void split_w_k(const float* __restrict__ W, __bf16* __restrict__ Wh,
               __bf16* __restrict__ Wl, int n4)
{
    int i = blockIdx.x * BDIM + threadIdx.x;
    if (i >= n4) return;
    float4 v = *(const float4*)(W + (size_t)i * 4);
    float vv[4] = {v.x, v.y, v.z, v.w};
    bf16x4 hv, lv;
    #pragma unroll
    for (int j = 0; j < 4; ++j) {
        __bf16 h = (__bf16)vv[j];
        hv[j] = h;
        lv[j] = (__bf16)(vv[j] - (float)h);
    }
    *(bf16x4*)(Wh + (size_t)i * 4) = hv;
    *(bf16x4*)(Wl + (size_t)i * 4) = lv;
}

// ---- A-side staging (fp32 activations, in-loop split) ----
template<int TR>
__device__ __forceinline__ void load_tile(const float* __restrict__ G, int ldg, int valid,
                                          float4* rg, int tid)
{
    #pragma unroll
    for (int i = 0; i < TR / 32; ++i) {
        int f = tid + i * 256;
        int r = f >> 3;
        int c = (f & 7) << 2;
        float4 v = make_float4(0.f, 0.f, 0.f, 0.f);
        if (r < valid) v = *(const float4*)(G + (size_t)r * ldg + c);
        rg[i] = v;
    }
}

template<int TR>
__device__ __forceinline__ void write_tile(const float4* rg, __bf16 (*H)[40], __bf16 (*Lo)[40], int tid)
{
    #pragma unroll
    for (int i = 0; i < TR / 32; ++i) {
        int f = tid + i * 256;
        int r = f >> 3;
        int c = (f & 7) << 2;
        float vv[4] = {rg[i].x, rg[i].y, rg[i].z, rg[i].w};
        bf16x4 hv, lv;
        #pragma unroll
        for (int j = 0; j < 4; ++j) {
            __bf16 h = (__bf16)vv[j];
            hv[j] = h;
            lv[j] = (__bf16)(vv[j] - (float)h);
        }
        *(bf16x4*)&H[r][c]  = hv;
        *(bf16x4*)&Lo[r][c] = lv;
    }
}

// ---- B-side staging (pre-split bf16 weights, no conversion) ----
template<int TR>
__device__ __forceinline__ void load_wtile(const __bf16* __restrict__ Wh, const __bf16* __restrict__ Wl,
                                           int ldb, int valid, bf16x8* rh, bf16x8* rl, int tid)
{
    #pragma unroll
    for (int i = 0; i < TR / 64; ++i) {
        int f = tid + i * 256;
        int r = f >> 2;
        int c = (f & 3) * 8;
        bf16x8 hv = {}, lv = {};
        if (r < valid) {
            hv = *(const bf16x8*)(Wh + (size_t)r * ldb + c);
            lv = *(const bf16x8*)(Wl + (size_t)r * ldb + c);
        }
        rh[i] = hv;
        rl[i] = lv;
    }
}

template<int TR>
__device__ __forceinline__ void store_wtile(const bf16x8* rh, const bf16x8* rl,
                                            __bf16 (*H)[40], __bf16 (*Lo)[40], int tid)
{
    #pragma unroll
    for (int i = 0; i < TR / 64; ++i) {
        int f = tid + i * 256;
        int r = f >> 2;
        int c = (f & 3) * 8;
        *(bf16x8*)&H[r][c]  = rh[i];
        *(bf16x8*)&Lo[r][c] = rl[i];
    }
}

// C = A[M,K] * W[N,K]^T, A fp32, W pre-split bf16 hi/lo. bf16x3 split-precision MFMA.
// Register-prefetch pipeline. FUSE: 0 none, 1 softplus(x+bias[n])
template<int BM, int BN, int FM, int FN, int FUSE>
__global__ __launch_bounds__(256)
void gemm_pw(const float* __restrict__ A, int lda,
             const __bf16* __restrict__ Bwh, const __bf16* __restrict__ Bwl, int ldb,
             float* __restrict__ C, int ldc,
             int M, int N, int Kchunk, long csplit_stride,
             const float* __restrict__ bias)
{
    __shared__ __bf16 Ah[BM][40], Al[BM][40], Bh[BN][40], Bl[BN][40];
    const int tid  = threadIdx.x;
    const int lane = tid & 63;
    const int wave = tid >> 6;
    const int wm = wave >> 1, wn = wave & 1;
    const int m0 = blockIdx.y * BM;
    const int n0 = blockIdx.x * BN;
    const long kbase = (long)blockIdx.z * Kchunk;
    const float*  Ap  = A   + (size_t)m0 * lda + kbase;
    const __bf16* Bph = Bwh + (size_t)n0 * ldb + kbase;
    const __bf16* Bpl = Bwl + (size_t)n0 * ldb + kbase;
    const int validA = min(BM, M - m0);
    const int validB = min(BN, N - n0);
    f32x4 acc[FM][FN] = {};
    const int fr = lane & 15;
    const int kq = (lane >> 4) * 8;

    float4 ra[BM / 32];
    bf16x8 rbh[BN / 64], rbl[BN / 64];
    load_tile<BM>(Ap, lda, validA, ra, tid);
    load_wtile<BN>(Bph, Bpl, ldb, validB, rbh, rbl, tid);

    for (int k0 = 0; k0 < Kchunk; k0 += 32) {
        write_tile<BM>(ra, Ah, Al, tid);
        store_wtile<BN>(rbh, rbl, Bh, Bl, tid);
        __syncthreads();
        if (k0 + 32 < Kchunk) {                 // prefetch next tile into regs
            load_tile<BM>(Ap + k0 + 32, lda, validA, ra, tid);
            load_wtile<BN>(Bph + k0 + 32, Bpl + k0 + 32, ldb, validB, rbh, rbl, tid);
        }
        bf16x8 ah[FM], al[FM], bh[FN], bl[FN];
        #pragma unroll
        for (int i = 0; i < FM; ++i) {
            int r = wm * (FM * 16) + i * 16 + fr;
            ah[i] = *(const bf16x8*)&Ah[r][kq];
            al[i] = *(const bf16x8*)&Al[r][kq];
        }
        #pragma unroll
        for (int j = 0; j < FN; ++j) {
            int r = wn * (FN * 16) + j * 16 + fr;
            bh[j] = *(const bf16x8*)&Bh[r][kq];
            bl[j] = *(const bf16x8*)&Bl[r][kq];
        }
        #pragma unroll
        for (int i = 0; i < FM; ++i)
            #pragma unroll
            for (int j = 0; j < FN; ++j) {
                acc[i][j] = __builtin_amdgcn_mfma_f32_16x16x32_bf16(ah[i], bh[j], acc[i][j], 0, 0, 0);
                acc[i][j] = __builtin_amdgcn_mfma_f32_16x16x32_bf16(ah[i], bl[j], acc[i][j], 0, 0, 0);
                acc[i][j] = __builtin_amdgcn_mfma_f32_16x16x32_bf16(al[i], bh[j], acc[i][j], 0, 0, 0);
            }
        __syncthreads();
    }

    float* Cp = C + (size_t)blockIdx.z * csplit_stride;
    #pragma unroll
    for (int i = 0; i < FM; ++i)
        #pragma unroll
        for (int j = 0; j < FN; ++j)
            #pragma unroll
            for (int r = 0; r < 4; ++r) {
                int gm = m0 + wm * (FM * 16) + i * 16 + (lane >> 4) * 4 + r;
                int gn = n0 + wn * (FN * 16) + j * 16 + (lane & 15);
                if (gm < M && gn < N) {
                    float v = acc[i][j][r];
                    if (FUSE == 1) { v += bias[gn]; v = (v > 20.f) ? v : log1pf(__expf(v)); }
                    Cp[(size_t)gm * ldc + gn] = v;
                }
            }
}

// sum split-K partials; FUSE: 0 none, 2 tanh(x + bias[n])
template<int FUSE>
__global__ __launch_bounds__(256)
void reduce_k(const float* __restrict__ part, float* __restrict__ C,
              int MN, int N, int S, long stride, const float* __restrict__ bias)
{
    int i = blockIdx.x * 256 + threadIdx.x;
    if (i >= MN) return;
    float s = 0.f;
    for (int j = 0; j < S; ++j) s += part[(size_t)j * stride + i];
    if (FUSE == 2) s = tanhf(s + bias[i % N]);
    C[i] = s;
}

// depthwise causal conv (width 4) + bias + SiLU over xi = xz[:, :DI]
__global__ __launch_bounds__(BDIM)
void conv_silu_k(const float* __restrict__ xz, const float* __restrict__ cw,
                 const float* __restrict__ cb, float* __restrict__ xc)
{
    int idx = blockIdx.x * BDIM + threadIdx.x;
    if (idx >= M1 * DI) return;
    int d = idx & (DI - 1);
    int m = idx >> 11;
    int b = m / L_, l = m - b * L_;
    float acc = cb[d];
    #pragma unroll
    for (int t = 0; t < 4; ++t) {
        int ls = l - 3 + t;
        if (ls >= 0)
            acc = fmaf(cw[d * 4 + t], xz[(size_t)(b * L_ + ls) * DXZ + d], acc);
    }
    xc[idx] = acc * sigmoidf_(acc);
}

// ---- chunked selective scan: thread-per-chain, 16 states in registers ----
__global__ __launch_bounds__(BDIM)
void scan_partial_k(const float* __restrict__ delta, const float* __restrict__ xc,
                    const float* __restrict__ xdbl, const float* __restrict__ A_log,
                    float* __restrict__ hpart, float* __restrict__ aprod)
{
    const int t = blockIdx.x * BDIM + threadIdx.x;
    const int d = t & (DI - 1);
    const int bc = t >> 11;
    const int b = bc / NC, c = bc - b * NC;
    const int l0 = c * LC;
    float Aa[NST];
    #pragma unroll
    for (int q = 0; q < 4; ++q) {
        float4 a4 = *(const float4*)(A_log + (size_t)d * NST + q * 4);
        Aa[q*4+0] = -__expf(a4.x); Aa[q*4+1] = -__expf(a4.y);
        Aa[q*4+2] = -__expf(a4.z); Aa[q*4+3] = -__expf(a4.w);
    }
    const float* dlt = delta + ((size_t)(b * L_ + l0)) * DI + d;
    const float* xcd = xc    + ((size_t)(b * L_ + l0)) * DI + d;
    const float* bp  = xdbl  + ((size_t)(b * L_ + l0)) * NXP + RNK;
    float h[NST] = {};
    float sdv = 0.f;
    for (int l = 0; l < LC; ++l) {
        float dv = dlt[(size_t)l * DI];
        float xv = xcd[(size_t)l * DI];
        const float4* b4 = (const float4*)(bp + (size_t)l * NXP);
        float dvx = dv * xv;
        sdv += dv;
        #pragma unroll
        for (int q = 0; q < 4; ++q) {
            float4 Bq = b4[q];
            float bb[4] = {Bq.x, Bq.y, Bq.z, Bq.w};
            #pragma unroll
            for (int j = 0; j < 4; ++j) {
                int n = q * 4 + j;
                float dA = __expf(dv * Aa[n]);
                h[n] = fmaf(dA, h[n], dvx * bb[j]);
            }
        }
    }
    float4* hp4 = (float4*)(hpart + (size_t)t * NST);
    float4* ap4 = (float4*)(aprod + (size_t)t * NST);
    #pragma unroll
    for (int q = 0; q < 4; ++q) {
        hp4[q] = make_float4(h[q*4], h[q*4+1], h[q*4+2], h[q*4+3]);
        ap4[q] = make_float4(__expf(Aa[q*4+0]*sdv), __expf(Aa[q*4+1]*sdv),
                             __expf(Aa[q*4+2]*sdv), __expf(Aa[q*4+3]*sdv));
    }
}

__global__ __launch_bounds__(BDIM)
void scan_fix_k(float* __restrict__ hpart, const float* __restrict__ aprod)
{
    const int i = blockIdx.x * BDIM + threadIdx.x;   // (b*DI + d)*16 + n
    if (i >= B_ * DI * NST) return;
    const int nn = i & (NST - 1);
    const int d  = (i >> 4) & (DI - 1);
    const int b  = i >> 15;
    float h = 0.f;
    for (int c = 0; c < NC; ++c) {
        size_t o = ((size_t)((b * NC + c) * DI + d)) * NST + nn;
        float hp = hpart[o];
        float ap = aprod[o];
        hpart[o] = h;                // hpre
        h = fmaf(ap, h, hp);
    }
}

__global__ __launch_bounds__(BDIM)
void scan_final_k(const float* __restrict__ xz, const float* __restrict__ xc,
                  const float* __restrict__ xdbl, const float* __restrict__ delta,
                  const float* __restrict__ A_log, const float* __restrict__ Dp,
                  const float* __restrict__ hpre, float* __restrict__ y)
{
    const int t = blockIdx.x * BDIM + threadIdx.x;
    const int d = t & (DI - 1);
    const int bc = t >> 11;
    const int b = bc / NC, c = bc - b * NC;
    const int l0 = c * LC;
    float Aa[NST];
    #pragma unroll
    for (int q = 0; q < 4; ++q) {
        float4 a4 = *(const float4*)(A_log + (size_t)d * NST + q * 4);
        Aa[q*4+0] = -__expf(a4.x); Aa[q*4+1] = -__expf(a4.y);
        Aa[q*4+2] = -__expf(a4.z); Aa[q*4+3] = -__expf(a4.w);
    }
    float h[NST];
    const float4* h4 = (const float4*)(hpre + (size_t)t * NST);
    #pragma unroll
    for (int q = 0; q < 4; ++q) {
        float4 hv = h4[q];
        h[q*4+0] = hv.x; h[q*4+1] = hv.y; h[q*4+2] = hv.z; h[q*4+3] = hv.w;
    }
    const float Dd = Dp[d];
    const float* dlt = delta + ((size_t)(b * L_ + l0)) * DI + d;
    const float* xcd = xc    + ((size_t)(b * L_ + l0)) * DI + d;
    const float* bp  = xdbl  + ((size_t)(b * L_ + l0)) * NXP + RNK;
    const float* zp  = xz    + ((size_t)(b * L_ + l0)) * DXZ + DI + d;
    float* yp = y + ((size_t)(b * L_ + l0)) * DI + d;
    for (int l = 0; l < LC; ++l) {
        float dv = dlt[(size_t)l * DI];
        float xv = xcd[(size_t)l * DI];
        const float4* b4 = (const float4*)(bp + (size_t)l * NXP);
        float dvx = dv * xv;
        float p = 0.f;
        #pragma unroll
        for (int q = 0; q < 4; ++q) {
            float4 Bq = b4[q];
            float4 Cq = b4[4 + q];
            float bb[4] = {Bq.x, Bq.y, Bq.z, Bq.w};
            float cc[4] = {Cq.x, Cq.y, Cq.z, Cq.w};
            #pragma unroll
            for (int j = 0; j < 4; ++j) {
                int n = q * 4 + j;
                float dA = __expf(dv * Aa[n]);
                h[n] = fmaf(dA, h[n], dvx * bb[j]);
                p = fmaf(h[n], cc[j], p);
            }
        }
        float zv = zp[(size_t)l * DXZ];
        float yv = fmaf(xv, Dd, p);
        yv *= zv * sigmoidf_(zv);
        yp[(size_t)l * DI] = yv;
    }
}

extern "C" void kernel_launch(void* const* d_in, const int* in_sizes, int n_in,
                              void* d_out, int out_size, void* d_ws, size_t ws_size,
                              hipStream_t stream) {
    const float* x         = (const float*)d_in[0];
    const float* in_proj_w = (const float*)d_in[1];
    const float* conv_w    = (const float*)d_in[2];
    const float* conv_b    = (const float*)d_in[3];
    const float* x_proj_w  = (const float*)d_in[4];
    const float* dt_proj_w = (const float*)d_in[5];
    const float* dt_proj_b = (const float*)d_in[6];
    const float* A_log     = (const float*)d_in[7];
    const float* Dp        = (const float*)d_in[8];
    const float* out_proj_w= (const float*)d_in[9];
    const float* fc1_w     = (const float*)d_in[10];
    const float* fc1_b     = (const float*)d_in[11];
    float* out = (float*)d_out;

    float* ws    = (float*)d_ws;
    // static fp32 regions (floats): [same 87.3 MB footprint as R10]
    float* xz    = ws;                               // +0        size 8,192,000
    float* xc    = xz + (size_t)M1 * DXZ;            // +8192000  size 4,096,000
    float* xdbl  = xc + (size_t)M1 * DI;             // +12288000 size 192,000
    float* delta = xdbl + (size_t)M1 * NXP;          // +12480000 size 4,096,000
    float* hpart = delta + (size_t)M1 * DI;          // +16576000 size 2,621,440
    float* aprod = hpart + (size_t)B_ * NC * DI * NST; // +19197440 size 2,621,440
    float* y     = delta;   // alias: scan writes in place
    float* partx = delta;   // alias: x_proj partials (consumed before delta written)
    float* partO = xz;      // alias: out_proj partials (xz dead after scan_final)
    float* ym    = xc;      // alias: out_proj result (xc dead after scan_final)
    float* partf = delta;   // alias: fc1 partials (y dead after out_proj)

    // time-multiplexed bf16 weight buffers in dead regions:
    __bf16* W1h = (__bf16*)hpart;                 // in_proj hi (8.39MB of 10.49MB) [live: step 1-2]
    __bf16* W1l = (__bf16*)aprod;                 // in_proj lo                    [live: step 1-2]
    __bf16* xph = (__bf16*)hpart;                 // x_proj hi  (0.39MB)           [live: steps 4-6]
    __bf16* xpl = xph + (size_t)NXP * DI;
    __bf16* dph = xpl + (size_t)NXP * DI;         // dt_proj hi (0.26MB)
    __bf16* dpl = dph + (size_t)DI * RNK;
    __bf16* W4h = (__bf16*)xc;                    // out_proj hi (4.19MB of 16.4MB) [live: steps 12-13]
    __bf16* W4l = W4h + (size_t)DM * DI;
    __bf16* f1h = (__bf16*)xz;                    // fc1 hi (20.97MB of 32.8MB)     [live: steps 15-16]
    __bf16* f1l = (__bf16*)hpart;                 // fc1 lo (20.97MB of 20.97MB)    [live: steps 15-16]

    dim3 blk(BDIM);
    // 1) split in_proj_w
    split_w_k<<<(DXZ*DM/4 + 255)/256, blk, 0, stream>>>(in_proj_w, W1h, W1l, DXZ*DM/4);
    // 2) xz = x @ in_proj_w^T  (128x128 tile, 512 blocks)
    gemm_pw<128,128,4,4,0><<<dim3(DXZ/128, (M1+127)/128, 1), blk, 0, stream>>>(
        x, DM, W1h, W1l, DM, xz, DXZ, M1, DXZ, DM, 0, nullptr);
    // 3) xc = silu(causal_conv4(xz[:, :DI]) + conv_b)
    conv_silu_k<<<(M1*DI + BDIM-1)/BDIM, blk, 0, stream>>>(xz, conv_w, conv_b, xc);
    // 4-5) split x_proj_w, dt_proj_w (in_proj weights dead)
    split_w_k<<<(NXP*DI/4 + 255)/256, blk, 0, stream>>>(x_proj_w, xph, xpl, NXP*DI/4);
    split_w_k<<<(DI*RNK/4 + 255)/256, blk, 0, stream>>>(dt_proj_w, dph, dpl, DI*RNK/4);
    // 6) x_proj split-K=8 (512 blocks)
    gemm_pw<64,64,2,2,0><<<dim3((NXP+63)/64, (M1+63)/64, 8), blk, 0, stream>>>(
        xc, DI, xph, xpl, DI, partx, NXP, M1, NXP, DI/8, (long)M1*NXP, nullptr);
    // 7) xdbl = sum partials
    reduce_k<0><<<(M1*NXP + 255)/256, blk, 0, stream>>>(
        partx, xdbl, M1*NXP, NXP, 8, (long)M1*NXP, nullptr);
    // 8) delta = softplus(xdbl[:, :64] @ dt_proj_w^T + dt_proj_b)
    gemm_pw<64,64,2,2,1><<<dim3(DI/64, (M1+63)/64, 1), blk, 0, stream>>>(
        xdbl, NXP, dph, dpl, RNK, delta, DI, M1, DI, RNK, 0, dt_proj_b);
    // 9-11) chunked selective scan (overwrites hpart/aprod; weights there are dead)
    scan_partial_k<<<(B_*NC*DI)/BDIM, blk, 0, stream>>>(
        delta, xc, xdbl, A_log, hpart, aprod);
    scan_fix_k<<<(B_*DI*NST + BDIM-1)/BDIM, blk, 0, stream>>>(hpart, aprod);
    scan_final_k<<<(B_*NC*DI)/BDIM, blk, 0, stream>>>(
        xz, xc, xdbl, delta, A_log, Dp, hpart, y);
    // 12) split out_proj_w into dead xc region
    split_w_k<<<(DM*DI/4 + 255)/256, blk, 0, stream>>>(out_proj_w, W4h, W4l, DM*DI/4);
    // 13) out_proj split-K=4 (2048 blocks): partO = y @ out_proj_w^T chunks
    gemm_pw<64,64,2,2,0><<<dim3(DM/64, (M1+63)/64, 4), blk, 0, stream>>>(
        y, DI, W4h, W4l, DI, partO, DM, M1, DM, DI/4, (long)M1*DM, nullptr);
    // 14) ym = sum partials (overwrites W4 — dead now)
    reduce_k<0><<<(M1*DM + 255)/256, blk, 0, stream>>>(
        partO, ym, M1*DM, DM, 4, (long)M1*DM, nullptr);
    // 15) split fc1_w into dead xz + hpart/aprod regions
    split_w_k<<<(DM*K2/4 + 255)/256, blk, 0, stream>>>(fc1_w, f1h, f1l, DM*K2/4);
    // 16) fc1 split-K=20 (1280 blocks)
    gemm_pw<64,64,2,2,0><<<dim3(DM/64, (M2+63)/64, 20), blk, 0, stream>>>(
        ym, K2, f1h, f1l, K2, partf, DM, M2, DM, K2/20, (long)M2*DM, nullptr);
    // 17) out = tanh(sum partials + fc1_b)
    reduce_k<2><<<(M2*DM + 255)/256, blk, 0, stream>>>(
        partf, out, M2*DM, DM, 20, (long)M2*DM, fc1_b);
    (void)in_sizes; (void)n_in; (void)out_size; (void)ws_size;
}